// Round 6
// baseline (39.588 us; speedup 1.0000x reference)
//
#include <hip/hip_runtime.h>

// MapLoss: fused masked-MSE + pos/neg split loss over (32, 512, 512) f32 maps.
//
// Hot path: for these inputs (gt ~ U[0,1)), n_pos ~ 0.35-0.4*N >> N/4, so
// k = min(3*n_pos, n_neg) == n_neg for every row -> hard-negative top-k ==
// "mean over all negatives"; n_pos > 0 always (no top-500 fallback). The
// streaming pass only needs per-(sample,map) {pos_sum, neg_sum, n_pos}.
//
// R3 lesson: last-block fused reduction regressed 3x (per-block device fence).
// R4/R5 lesson: forced load-ILP is both un-forcible at source level AND
// unnecessary (Little's law: ~9 wave-wide loads/CU suffice; we have ~70).
// R6: pass1 is within ~15% of the external copy ceiling (5.4 of 6.3 TB/s);
// the residual is the static-assignment tail (one generation of 8 blocks/CU,
// no backfill). Finer quanta: 4096 blocks x 2 float4/stream/thread.

#define NPS (512 * 512)          // elements per sample
#define BPS 128                  // blocks per sample (pass1)
#define EPB 2048                 // elements per block: 256 thr * 2 float4
#define NB 32                    // batch

constexpr float THR_REGION = 0.6f;
constexpr float THR_AFF    = 0.65f;

// ---------------- pass 1: streaming fused accumulate ----------------
// grid (BPS, NB) = 4096 blocks x 256 thr. part[b][blk][6] =
// {posSumR, negSumR, cntR, posSumA, negSumA, cntA}. No atomics: deterministic.
__global__ __launch_bounds__(256) void map_loss_pass1(
    const float* __restrict__ rg, const float* __restrict__ ag,
    const float* __restrict__ rp, const float* __restrict__ ap,
    const float* __restrict__ mk, float* __restrict__ part) {
  const int b   = blockIdx.y;
  const int tid = threadIdx.x;
  const size_t sbase = (size_t)b * NPS + (size_t)blockIdx.x * EPB + (size_t)tid * 4;

  const float4* Gr = reinterpret_cast<const float4*>(rg + sbase);
  const float4* Ga = reinterpret_cast<const float4*>(ag + sbase);
  const float4* Pr = reinterpret_cast<const float4*>(rp + sbase);
  const float4* Pa = reinterpret_cast<const float4*>(ap + sbase);
  const float4* Mm = reinterpret_cast<const float4*>(mk + sbase);

  float v[6] = {0.f, 0.f, 0.f, 0.f, 0.f, 0.f};  // posR negR cntR posA negA cntA

#pragma unroll
  for (int jj = 0; jj < 2; ++jj) {
    const float4 g_r = Gr[jj * 256];   // stride 1024 floats between slabs
    const float4 g_a = Ga[jj * 256];
    const float4 p_r = Pr[jj * 256];
    const float4 p_a = Pa[jj * 256];
    const float4 m_4 = Mm[jj * 256];
    const float* gr = reinterpret_cast<const float*>(&g_r);
    const float* ga = reinterpret_cast<const float*>(&g_a);
    const float* pr = reinterpret_cast<const float*>(&p_r);
    const float* pa = reinterpret_cast<const float*>(&p_a);
    const float* mm = reinterpret_cast<const float*>(&m_4);
#pragma unroll
    for (int j = 0; j < 4; ++j) {
      const float m = mm[j];
      {  // region
        const float g = gr[j];
        float p = pr[j];
        const bool pos = g > THR_REGION;
        if (pos && p > 1.0f) p = 1.0f;
        const float d = p - g;
        const float l = d * d * m;
        if (pos) { v[0] += l; v[2] += 1.0f; } else { v[1] += l; }
      }
      {  // affinity
        const float g = ga[j];
        float p = pa[j];
        const bool pos = g > THR_AFF;
        if (pos && p > 1.0f) p = 1.0f;
        const float d = p - g;
        const float l = d * d * m;
        if (pos) { v[3] += l; v[5] += 1.0f; } else { v[4] += l; }
      }
    }
  }

  // wave64 shuffle reduce, then cross-wave via LDS
#pragma unroll
  for (int q = 0; q < 6; ++q)
#pragma unroll
    for (int off = 32; off > 0; off >>= 1)
      v[q] += __shfl_down(v[q], off, 64);

  __shared__ float sh[4][6];
  const int lane = tid & 63, wid = tid >> 6;
  if (lane == 0) {
#pragma unroll
    for (int q = 0; q < 6; ++q) sh[wid][q] = v[q];
  }
  __syncthreads();
  if (tid < 6) {
    const float s = sh[0][tid] + sh[1][tid] + sh[2][tid] + sh[3][tid];
    part[((size_t)b * BPS + blockIdx.x) * 6 + tid] = s;
  }
}

// ---------------- exact serial radix-select (rare paths only) ----------------
// Sum of top-k of the per-element loss map for one (sample,map) row. Values are
// >= 0 so float bit order == value order. 4 passes of 256-bin byte histograms.
__device__ float topk_sum_row(const float* __restrict__ gt,
                              const float* __restrict__ pd,
                              const float* __restrict__ mm,
                              float thr, int k, bool negOnly) {
  unsigned prefix = 0;
  float sum_def = 0.f;
  int want = k;
  for (int shift = 24; shift >= 0; shift -= 8) {
    unsigned cnt[256];
    float bsum[256];
    for (int i = 0; i < 256; ++i) { cnt[i] = 0; bsum[i] = 0.f; }
    for (int j = 0; j < NPS; ++j) {
      const float g = gt[j];
      const bool pos = g > thr;
      if (negOnly && pos) continue;
      float p = pd[j];
      if (pos && p > 1.0f) p = 1.0f;
      const float d = p - g;
      const float vv = d * d * mm[j];
      const unsigned u = __float_as_uint(vv);
      if (shift < 24 && (u >> (shift + 8)) != (prefix >> (shift + 8))) continue;
      const unsigned bin = (u >> shift) & 255u;
      cnt[bin]++;
      bsum[bin] += vv;
    }
    int bin = 255;
    for (; bin > 0; --bin) {
      if ((int)cnt[bin] < want) { want -= (int)cnt[bin]; sum_def += bsum[bin]; }
      else break;
    }
    prefix |= ((unsigned)bin) << shift;
  }
  sum_def += (float)want * __uint_as_float(prefix);
  return sum_def;
}

// ---------------- pass 2: parallel finalize ----------------
// 1 block x 256 threads. Row r = (map,sample) handled by 4 lanes; each lane
// sums 32 of the 128 partial-triples, then 2 shfl_xor steps combine the group.
__global__ __launch_bounds__(256) void map_loss_pass2(
    const float* __restrict__ part,
    const float* __restrict__ rg, const float* __restrict__ ag,
    const float* __restrict__ rp, const float* __restrict__ ap,
    const float* __restrict__ mk, float* __restrict__ out) {
  const int t = threadIdx.x;
  const int row = t >> 2;        // 0..63
  const int sub = t & 3;
  const int mapA = row >> 5;     // 0 = region, 1 = affinity
  const int b = row & 31;

  float posSum = 0.f, negSum = 0.f, cntF = 0.f;
  for (int blk = sub; blk < BPS; blk += 4) {
    const float* p = part + ((size_t)b * BPS + blk) * 6 + mapA * 3;
    posSum += p[0];
    negSum += p[1];
    cntF   += p[2];
  }
#pragma unroll
  for (int msk = 1; msk <= 2; msk <<= 1) {
    posSum += __shfl_xor(posSum, msk, 64);
    negSum += __shfl_xor(negSum, msk, 64);
    cntF   += __shfl_xor(cntF, msk, 64);
  }

  __shared__ float sh[64];
  if (sub == 0) {
    const int npos = (int)cntF;           // partial counts are exact integers
    const int nneg = NPS - npos;
    long long k = 3LL * npos;
    if (k > nneg) k = nneg;

    const float thr = mapA ? THR_AFF : THR_REGION;
    const float* gt = (mapA ? ag : rg) + (size_t)b * NPS;
    const float* pd = (mapA ? ap : rp) + (size_t)b * NPS;
    const float* mm = mk + (size_t)b * NPS;

    float per_sample;
    if (npos > 0) {
      const float pos_loss = posSum / (float)npos;
      float neg_loss = 0.f;
      if (k > 0) {
        if (k == (long long)nneg) {
          neg_loss = negSum / (float)nneg;             // hot path
        } else {
          neg_loss = topk_sum_row(gt, pd, mm, thr, (int)k, true) / (float)k;
        }
      }
      per_sample = pos_loss + neg_loss;
    } else {
      per_sample = topk_sum_row(gt, pd, mm, thr, 500, false) / 500.0f;
    }
    sh[row] = per_sample;
  }
  __syncthreads();
  if (t == 0) {
    float char_sum = 0.f, affi_sum = 0.f;
    for (int i = 0; i < 32; ++i) { char_sum += sh[i]; affi_sum += sh[32 + i]; }
    out[0] = 2.0f * char_sum / (float)NB + affi_sum / (float)NB;
  }
}

extern "C" void kernel_launch(void* const* d_in, const int* in_sizes, int n_in,
                              void* d_out, int out_size, void* d_ws, size_t ws_size,
                              hipStream_t stream) {
  const float* rg = (const float*)d_in[0];
  const float* ag = (const float*)d_in[1];
  const float* rp = (const float*)d_in[2];
  const float* ap = (const float*)d_in[3];
  const float* mk = (const float*)d_in[4];
  float* out = (float*)d_out;
  float* part = (float*)d_ws;  // [NB][BPS][6] f32 = 96 KB, fully rewritten per call

  dim3 grid1(BPS, NB);
  map_loss_pass1<<<grid1, 256, 0, stream>>>(rg, ag, rp, ap, mk, part);
  map_loss_pass2<<<1, 256, 0, stream>>>(part, rg, ag, rp, ap, mk, out);
}

// Round 7
// 31.966 us; speedup vs baseline: 1.2385x; 1.2385x over previous
//
#include <hip/hip_runtime.h>

// MapLoss: fused masked-MSE + pos/neg split loss over (32, 512, 512) f32 maps.
//
// Hot path: for these inputs (gt ~ U[0,1)), n_pos ~ 0.35-0.4*N >> N/4, so
// k = min(3*n_pos, n_neg) == n_neg for every row -> hard-negative top-k ==
// "mean over all negatives"; n_pos > 0 always (no top-500 fallback). The
// streaming pass only needs per-(sample,map) {pos_sum, neg_sum, n_pos}.
//
// R3: last-block fused reduction regressed 3x (per-block device fence).
// R4/R5: forced load-ILP un-forcible at source level AND unnecessary.
// R6: finer quanta regressed; block-count curve is monotone (4096>2048>1024),
//     per-block fixed cost dominates -> R7 tries 512 blocks x EPB 16384.

#define NPS (512 * 512)          // elements per sample
#define BPS 16                   // blocks per sample (pass1)
#define EPB 16384                // elements per block: 256 thr * 16 float4
#define NB 32                    // batch

constexpr float THR_REGION = 0.6f;
constexpr float THR_AFF    = 0.65f;

// ---------------- pass 1: streaming fused accumulate ----------------
// grid (BPS, NB) = 512 blocks x 256 thr. part[b][blk][6] =
// {posSumR, negSumR, cntR, posSumA, negSumA, cntA}. No atomics: deterministic.
__global__ __launch_bounds__(256) void map_loss_pass1(
    const float* __restrict__ rg, const float* __restrict__ ag,
    const float* __restrict__ rp, const float* __restrict__ ap,
    const float* __restrict__ mk, float* __restrict__ part) {
  const int b   = blockIdx.y;
  const int tid = threadIdx.x;
  const size_t sbase = (size_t)b * NPS + (size_t)blockIdx.x * EPB + (size_t)tid * 4;

  const float4* Gr = reinterpret_cast<const float4*>(rg + sbase);
  const float4* Ga = reinterpret_cast<const float4*>(ag + sbase);
  const float4* Pr = reinterpret_cast<const float4*>(rp + sbase);
  const float4* Pa = reinterpret_cast<const float4*>(ap + sbase);
  const float4* Mm = reinterpret_cast<const float4*>(mk + sbase);

  float v[6] = {0.f, 0.f, 0.f, 0.f, 0.f, 0.f};  // posR negR cntR posA negA cntA

#pragma unroll
  for (int jj = 0; jj < 16; ++jj) {
    const float4 g_r = Gr[jj * 256];   // stride 1024 floats between slabs
    const float4 g_a = Ga[jj * 256];
    const float4 p_r = Pr[jj * 256];
    const float4 p_a = Pa[jj * 256];
    const float4 m_4 = Mm[jj * 256];
    const float* gr = reinterpret_cast<const float*>(&g_r);
    const float* ga = reinterpret_cast<const float*>(&g_a);
    const float* pr = reinterpret_cast<const float*>(&p_r);
    const float* pa = reinterpret_cast<const float*>(&p_a);
    const float* mm = reinterpret_cast<const float*>(&m_4);
#pragma unroll
    for (int j = 0; j < 4; ++j) {
      const float m = mm[j];
      {  // region
        const float g = gr[j];
        float p = pr[j];
        const bool pos = g > THR_REGION;
        if (pos && p > 1.0f) p = 1.0f;
        const float d = p - g;
        const float l = d * d * m;
        if (pos) { v[0] += l; v[2] += 1.0f; } else { v[1] += l; }
      }
      {  // affinity
        const float g = ga[j];
        float p = pa[j];
        const bool pos = g > THR_AFF;
        if (pos && p > 1.0f) p = 1.0f;
        const float d = p - g;
        const float l = d * d * m;
        if (pos) { v[3] += l; v[5] += 1.0f; } else { v[4] += l; }
      }
    }
  }

  // wave64 shuffle reduce, then cross-wave via LDS
#pragma unroll
  for (int q = 0; q < 6; ++q)
#pragma unroll
    for (int off = 32; off > 0; off >>= 1)
      v[q] += __shfl_down(v[q], off, 64);

  __shared__ float sh[4][6];
  const int lane = tid & 63, wid = tid >> 6;
  if (lane == 0) {
#pragma unroll
    for (int q = 0; q < 6; ++q) sh[wid][q] = v[q];
  }
  __syncthreads();
  if (tid < 6) {
    const float s = sh[0][tid] + sh[1][tid] + sh[2][tid] + sh[3][tid];
    part[((size_t)b * BPS + blockIdx.x) * 6 + tid] = s;
  }
}

// ---------------- exact serial radix-select (rare paths only) ----------------
// Sum of top-k of the per-element loss map for one (sample,map) row. Values are
// >= 0 so float bit order == value order. 4 passes of 256-bin byte histograms.
__device__ float topk_sum_row(const float* __restrict__ gt,
                              const float* __restrict__ pd,
                              const float* __restrict__ mm,
                              float thr, int k, bool negOnly) {
  unsigned prefix = 0;
  float sum_def = 0.f;
  int want = k;
  for (int shift = 24; shift >= 0; shift -= 8) {
    unsigned cnt[256];
    float bsum[256];
    for (int i = 0; i < 256; ++i) { cnt[i] = 0; bsum[i] = 0.f; }
    for (int j = 0; j < NPS; ++j) {
      const float g = gt[j];
      const bool pos = g > thr;
      if (negOnly && pos) continue;
      float p = pd[j];
      if (pos && p > 1.0f) p = 1.0f;
      const float d = p - g;
      const float vv = d * d * mm[j];
      const unsigned u = __float_as_uint(vv);
      if (shift < 24 && (u >> (shift + 8)) != (prefix >> (shift + 8))) continue;
      const unsigned bin = (u >> shift) & 255u;
      cnt[bin]++;
      bsum[bin] += vv;
    }
    int bin = 255;
    for (; bin > 0; --bin) {
      if ((int)cnt[bin] < want) { want -= (int)cnt[bin]; sum_def += bsum[bin]; }
      else break;
    }
    prefix |= ((unsigned)bin) << shift;
  }
  sum_def += (float)want * __uint_as_float(prefix);
  return sum_def;
}

// ---------------- pass 2: parallel finalize ----------------
// 1 block x 256 threads. Row r = (map,sample) handled by 4 lanes; each lane
// sums 4 of the 16 partial-triples, then 2 shfl_xor steps combine the group.
__global__ __launch_bounds__(256) void map_loss_pass2(
    const float* __restrict__ part,
    const float* __restrict__ rg, const float* __restrict__ ag,
    const float* __restrict__ rp, const float* __restrict__ ap,
    const float* __restrict__ mk, float* __restrict__ out) {
  const int t = threadIdx.x;
  const int row = t >> 2;        // 0..63
  const int sub = t & 3;
  const int mapA = row >> 5;     // 0 = region, 1 = affinity
  const int b = row & 31;

  float posSum = 0.f, negSum = 0.f, cntF = 0.f;
  for (int blk = sub; blk < BPS; blk += 4) {
    const float* p = part + ((size_t)b * BPS + blk) * 6 + mapA * 3;
    posSum += p[0];
    negSum += p[1];
    cntF   += p[2];
  }
#pragma unroll
  for (int msk = 1; msk <= 2; msk <<= 1) {
    posSum += __shfl_xor(posSum, msk, 64);
    negSum += __shfl_xor(negSum, msk, 64);
    cntF   += __shfl_xor(cntF, msk, 64);
  }

  __shared__ float sh[64];
  if (sub == 0) {
    const int npos = (int)cntF;           // partial counts are exact integers
    const int nneg = NPS - npos;
    long long k = 3LL * npos;
    if (k > nneg) k = nneg;

    const float thr = mapA ? THR_AFF : THR_REGION;
    const float* gt = (mapA ? ag : rg) + (size_t)b * NPS;
    const float* pd = (mapA ? ap : rp) + (size_t)b * NPS;
    const float* mm = mk + (size_t)b * NPS;

    float per_sample;
    if (npos > 0) {
      const float pos_loss = posSum / (float)npos;
      float neg_loss = 0.f;
      if (k > 0) {
        if (k == (long long)nneg) {
          neg_loss = negSum / (float)nneg;             // hot path
        } else {
          neg_loss = topk_sum_row(gt, pd, mm, thr, (int)k, true) / (float)k;
        }
      }
      per_sample = pos_loss + neg_loss;
    } else {
      per_sample = topk_sum_row(gt, pd, mm, thr, 500, false) / 500.0f;
    }
    sh[row] = per_sample;
  }
  __syncthreads();
  if (t == 0) {
    float char_sum = 0.f, affi_sum = 0.f;
    for (int i = 0; i < 32; ++i) { char_sum += sh[i]; affi_sum += sh[32 + i]; }
    out[0] = 2.0f * char_sum / (float)NB + affi_sum / (float)NB;
  }
}

extern "C" void kernel_launch(void* const* d_in, const int* in_sizes, int n_in,
                              void* d_out, int out_size, void* d_ws, size_t ws_size,
                              hipStream_t stream) {
  const float* rg = (const float*)d_in[0];
  const float* ag = (const float*)d_in[1];
  const float* rp = (const float*)d_in[2];
  const float* ap = (const float*)d_in[3];
  const float* mk = (const float*)d_in[4];
  float* out = (float*)d_out;
  float* part = (float*)d_ws;  // [NB][BPS][6] f32 = 12 KB, fully rewritten per call

  dim3 grid1(BPS, NB);
  map_loss_pass1<<<grid1, 256, 0, stream>>>(rg, ag, rp, ap, mk, part);
  map_loss_pass2<<<1, 256, 0, stream>>>(part, rg, ag, rp, ap, mk, out);
}

// Round 8
// 31.742 us; speedup vs baseline: 1.2472x; 1.0071x over previous
//
#include <hip/hip_runtime.h>

// MapLoss: fused masked-MSE + pos/neg split loss over (32, 512, 512) f32 maps.
//
// Hot path: for these inputs (gt ~ U[0,1)), n_pos ~ 0.35-0.4*N >> N/4, so
// k = min(3*n_pos, n_neg) == n_neg for every row -> hard-negative top-k ==
// "mean over all negatives"; n_pos > 0 always (no top-500 fallback). The
// streaming pass only needs per-(sample,map) {pos_sum, neg_sum, n_pos}.
//
// R3: last-block fused reduction regressed 3x (per-block device fence).
// R4/R5: forced load-ILP un-forcible at source level AND unnecessary.
// R6/R7: block-count curve monotone (4096 39.6 > 2048 34.5 > 1024 33.0 >
//        512 32.0) -- per-block fixed cost dominates. R8: 256 blocks x 512
//        threads = same 8 waves/CU as R7 but half the block overhead.

#define NPS (512 * 512)          // elements per sample
#define BPS 8                    // blocks per sample (pass1)
#define EPB 32768                // elements per block: 512 thr * 16 float4
#define NB 32                    // batch

constexpr float THR_REGION = 0.6f;
constexpr float THR_AFF    = 0.65f;

// ---------------- pass 1: streaming fused accumulate ----------------
// grid (BPS, NB) = 256 blocks x 512 thr (1 block/CU, 8 waves). part[b][blk][6]
// = {posSumR, negSumR, cntR, posSumA, negSumA, cntA}. No atomics.
__global__ __launch_bounds__(512) void map_loss_pass1(
    const float* __restrict__ rg, const float* __restrict__ ag,
    const float* __restrict__ rp, const float* __restrict__ ap,
    const float* __restrict__ mk, float* __restrict__ part) {
  const int b   = blockIdx.y;
  const int tid = threadIdx.x;
  const size_t sbase = (size_t)b * NPS + (size_t)blockIdx.x * EPB + (size_t)tid * 4;

  const float4* Gr = reinterpret_cast<const float4*>(rg + sbase);
  const float4* Ga = reinterpret_cast<const float4*>(ag + sbase);
  const float4* Pr = reinterpret_cast<const float4*>(rp + sbase);
  const float4* Pa = reinterpret_cast<const float4*>(ap + sbase);
  const float4* Mm = reinterpret_cast<const float4*>(mk + sbase);

  float v[6] = {0.f, 0.f, 0.f, 0.f, 0.f, 0.f};  // posR negR cntR posA negA cntA

#pragma unroll
  for (int jj = 0; jj < 16; ++jj) {
    const float4 g_r = Gr[jj * 512];   // stride 2048 floats between slabs
    const float4 g_a = Ga[jj * 512];
    const float4 p_r = Pr[jj * 512];
    const float4 p_a = Pa[jj * 512];
    const float4 m_4 = Mm[jj * 512];
    const float* gr = reinterpret_cast<const float*>(&g_r);
    const float* ga = reinterpret_cast<const float*>(&g_a);
    const float* pr = reinterpret_cast<const float*>(&p_r);
    const float* pa = reinterpret_cast<const float*>(&p_a);
    const float* mm = reinterpret_cast<const float*>(&m_4);
#pragma unroll
    for (int j = 0; j < 4; ++j) {
      const float m = mm[j];
      {  // region
        const float g = gr[j];
        float p = pr[j];
        const bool pos = g > THR_REGION;
        if (pos && p > 1.0f) p = 1.0f;
        const float d = p - g;
        const float l = d * d * m;
        if (pos) { v[0] += l; v[2] += 1.0f; } else { v[1] += l; }
      }
      {  // affinity
        const float g = ga[j];
        float p = pa[j];
        const bool pos = g > THR_AFF;
        if (pos && p > 1.0f) p = 1.0f;
        const float d = p - g;
        const float l = d * d * m;
        if (pos) { v[3] += l; v[5] += 1.0f; } else { v[4] += l; }
      }
    }
  }

  // wave64 shuffle reduce, then cross-wave via LDS (8 waves)
#pragma unroll
  for (int q = 0; q < 6; ++q)
#pragma unroll
    for (int off = 32; off > 0; off >>= 1)
      v[q] += __shfl_down(v[q], off, 64);

  __shared__ float sh[8][6];
  const int lane = tid & 63, wid = tid >> 6;
  if (lane == 0) {
#pragma unroll
    for (int q = 0; q < 6; ++q) sh[wid][q] = v[q];
  }
  __syncthreads();
  if (tid < 6) {
    float s = 0.f;
#pragma unroll
    for (int w = 0; w < 8; ++w) s += sh[w][tid];
    part[((size_t)b * BPS + blockIdx.x) * 6 + tid] = s;
  }
}

// ---------------- exact serial radix-select (rare paths only) ----------------
// Sum of top-k of the per-element loss map for one (sample,map) row. Values are
// >= 0 so float bit order == value order. 4 passes of 256-bin byte histograms.
__device__ float topk_sum_row(const float* __restrict__ gt,
                              const float* __restrict__ pd,
                              const float* __restrict__ mm,
                              float thr, int k, bool negOnly) {
  unsigned prefix = 0;
  float sum_def = 0.f;
  int want = k;
  for (int shift = 24; shift >= 0; shift -= 8) {
    unsigned cnt[256];
    float bsum[256];
    for (int i = 0; i < 256; ++i) { cnt[i] = 0; bsum[i] = 0.f; }
    for (int j = 0; j < NPS; ++j) {
      const float g = gt[j];
      const bool pos = g > thr;
      if (negOnly && pos) continue;
      float p = pd[j];
      if (pos && p > 1.0f) p = 1.0f;
      const float d = p - g;
      const float vv = d * d * mm[j];
      const unsigned u = __float_as_uint(vv);
      if (shift < 24 && (u >> (shift + 8)) != (prefix >> (shift + 8))) continue;
      const unsigned bin = (u >> shift) & 255u;
      cnt[bin]++;
      bsum[bin] += vv;
    }
    int bin = 255;
    for (; bin > 0; --bin) {
      if ((int)cnt[bin] < want) { want -= (int)cnt[bin]; sum_def += bsum[bin]; }
      else break;
    }
    prefix |= ((unsigned)bin) << shift;
  }
  sum_def += (float)want * __uint_as_float(prefix);
  return sum_def;
}

// ---------------- pass 2: parallel finalize ----------------
// 1 block x 256 threads. Row r = (map,sample) handled by 4 lanes; each lane
// sums 2 of the 8 partial-triples, then 2 shfl_xor steps combine the group.
__global__ __launch_bounds__(256) void map_loss_pass2(
    const float* __restrict__ part,
    const float* __restrict__ rg, const float* __restrict__ ag,
    const float* __restrict__ rp, const float* __restrict__ ap,
    const float* __restrict__ mk, float* __restrict__ out) {
  const int t = threadIdx.x;
  const int row = t >> 2;        // 0..63
  const int sub = t & 3;
  const int mapA = row >> 5;     // 0 = region, 1 = affinity
  const int b = row & 31;

  float posSum = 0.f, negSum = 0.f, cntF = 0.f;
  for (int blk = sub; blk < BPS; blk += 4) {
    const float* p = part + ((size_t)b * BPS + blk) * 6 + mapA * 3;
    posSum += p[0];
    negSum += p[1];
    cntF   += p[2];
  }
#pragma unroll
  for (int msk = 1; msk <= 2; msk <<= 1) {
    posSum += __shfl_xor(posSum, msk, 64);
    negSum += __shfl_xor(negSum, msk, 64);
    cntF   += __shfl_xor(cntF, msk, 64);
  }

  __shared__ float sh[64];
  if (sub == 0) {
    const int npos = (int)cntF;           // partial counts are exact integers
    const int nneg = NPS - npos;
    long long k = 3LL * npos;
    if (k > nneg) k = nneg;

    const float thr = mapA ? THR_AFF : THR_REGION;
    const float* gt = (mapA ? ag : rg) + (size_t)b * NPS;
    const float* pd = (mapA ? ap : rp) + (size_t)b * NPS;
    const float* mm = mk + (size_t)b * NPS;

    float per_sample;
    if (npos > 0) {
      const float pos_loss = posSum / (float)npos;
      float neg_loss = 0.f;
      if (k > 0) {
        if (k == (long long)nneg) {
          neg_loss = negSum / (float)nneg;             // hot path
        } else {
          neg_loss = topk_sum_row(gt, pd, mm, thr, (int)k, true) / (float)k;
        }
      }
      per_sample = pos_loss + neg_loss;
    } else {
      per_sample = topk_sum_row(gt, pd, mm, thr, 500, false) / 500.0f;
    }
    sh[row] = per_sample;
  }
  __syncthreads();
  if (t == 0) {
    float char_sum = 0.f, affi_sum = 0.f;
    for (int i = 0; i < 32; ++i) { char_sum += sh[i]; affi_sum += sh[32 + i]; }
    out[0] = 2.0f * char_sum / (float)NB + affi_sum / (float)NB;
  }
}

extern "C" void kernel_launch(void* const* d_in, const int* in_sizes, int n_in,
                              void* d_out, int out_size, void* d_ws, size_t ws_size,
                              hipStream_t stream) {
  const float* rg = (const float*)d_in[0];
  const float* ag = (const float*)d_in[1];
  const float* rp = (const float*)d_in[2];
  const float* ap = (const float*)d_in[3];
  const float* mk = (const float*)d_in[4];
  float* out = (float*)d_out;
  float* part = (float*)d_ws;  // [NB][BPS][6] f32 = 6 KB, fully rewritten per call

  dim3 grid1(BPS, NB);
  map_loss_pass1<<<grid1, 512, 0, stream>>>(rg, ag, rp, ap, mk, part);
  map_loss_pass2<<<1, 256, 0, stream>>>(part, rg, ag, rp, ap, mk, out);
}